// Round 10
// baseline (457.296 us; speedup 1.0000x reference)
//
#include <hip/hip_runtime.h>

// ---------------------------------------------------------------------------
// Fused multimodal net: l-MLP + 2 LSTMs (MFMA bf16) + tiny transformer head.
// N=4096, T=256, DA=74, DV=47, hidden=32.
//
// LSTM: lane-local recurrence + producer/consumer waves.
// Gate-row map G(rho,tau) = (rho&3)*32 + (rho>>2)*8 + tau  =>  lane (q,c)
// tile tau C-regs 0..3 = i,f,g,o of unit q*8+tau, sample c. Across tau=0..7
// the lane's h outputs are units q*8..q*8+7 of sample c — exactly its OWN
// B-fragment k-slice for the next step's h-MFMA. The h recurrence never
// leaves the lane: no LDS, no shuffle, no barrier. Wo epilogue B-operand is
// likewise the lane's hB.
// Block = 192 threads: wave0 = consumer (per step: 8 b128 gx reads + 8
// h-MFMAs + trans, zero intra-epoch sync). Waves 1,2 = producers: producer p
// computes gx[k] = bias + Wih@x[k] for step k = 2e+2+p (24/16 MFMAs), x
// staged via global_load_lds 8-slot ring with counted vmcnt (never 0),
// gx written to a 4-slot LDS ring. ONE barrier per 2-step epoch.
// ---------------------------------------------------------------------------

typedef float float4v __attribute__((ext_vector_type(4)));
typedef float float2v __attribute__((ext_vector_type(2)));
typedef short short8v __attribute__((ext_vector_type(8)));

#define N_SAMPLES 4096
#define T_STEPS 256

#define LGKM0 asm volatile("s_waitcnt lgkmcnt(0)" ::: "memory")

__device__ __forceinline__ short bf16r(float f) {
  unsigned u = __float_as_uint(f);
  u += 0x7FFFu + ((u >> 16) & 1u);
  return (short)(u >> 16);
}
__device__ __forceinline__ unsigned cvt_pk_bf16(float lo, float hi) {
  unsigned r;
  asm("v_cvt_pk_bf16_f32 %0, %1, %2" : "=v"(r) : "v"(lo), "v"(hi));
  return r;
}
__device__ __forceinline__ float sigm_(float x) {
  return __builtin_amdgcn_rcpf(1.0f +
                               __builtin_amdgcn_exp2f(x * -1.44269504f));
}
__device__ __forceinline__ float tanh_(float x) {
  return 1.0f - 2.0f * __builtin_amdgcn_rcpf(
                           1.0f + __builtin_amdgcn_exp2f(x * 2.88539009f));
}
__device__ __forceinline__ float4v mfma32(short8v a, short8v b, float4v c) {
  return __builtin_amdgcn_mfma_f32_16x16x32_bf16(a, b, c, 0, 0, 0);
}
__device__ __forceinline__ void gld16(const float* g, float* l) {
  __builtin_amdgcn_global_load_lds(
      (const __attribute__((address_space(1))) unsigned int*)g,
      (__attribute__((address_space(3))) unsigned int*)l, 16, 0, 0);
}

// LDS: x ring 8*16*74*4 = 37888 + gx ring 4*8*64*16 = 32768 + pad = 70720
#define SMEM_BYTES (8 * 16 * 74 * 4 + 4 * 8 * 64 * 16 + 64)

template <int D, int NK32, int LPS>
__device__ void lstm_ll(const float* __restrict__ x,
                        const float* __restrict__ Wih,
                        const float* __restrict__ Whh,
                        const float* __restrict__ bih,
                        const float* __restrict__ bhh,
                        const float* __restrict__ Wo,
                        const float* __restrict__ bo,
                        float* __restrict__ outf, int n0, char* smem) {
  constexpr int FPS = 16 * D;    // floats per x ring slot
  constexpr int UPS = FPS / 4;   // 16B units per slot
  constexpr int FULL = UPS / 64;
  constexpr int REM = UPS % 64;

  float* xbuf = (float*)smem;                 // [8][FPS]
  float* gxb = (float*)(smem + 8 * FPS * 4);  // [4][8][64][4] f32

  const int tid = threadIdx.x;
  const int wid = tid >> 6;   // 0 consumer; 1,2 producers
  const int lane = tid & 63;
  const int c = lane & 15;
  const int q = lane >> 4;

  auto stageslot = [&](int t) {
    const float* gs = x + (size_t)t * (N_SAMPLES * D) + (size_t)n0 * D;
    float* ls = xbuf + (t & 7) * FPS;
#pragma unroll
    for (int r = 0; r < FULL; ++r)
      gld16(gs + (r * 64 + lane) * 4, ls + r * 256);
    if (REM) {
      if (lane < REM) gld16(gs + (FULL * 64 + lane) * 4, ls + FULL * 256);
    }
  };

  if (wid == 0) {
    // ------------------------- CONSUMER ----------------------------------
    // wfh[tau]: A-row c -> Whh row G=(c&3)*32+(c>>2)*8+tau, k-elems q*8+e.
    short8v wfh[8];
#pragma unroll
    for (int tau = 0; tau < 8; ++tau) {
      const float* hr = Whh + ((c & 3) * 32 + (c >> 2) * 8 + tau) * 32;
#pragma unroll
      for (int e = 0; e < 8; ++e) wfh[tau][e] = bf16r(hr[q * 8 + e]);
    }
    short8v hB = {0, 0, 0, 0, 0, 0, 0, 0};
    float cst[8];
#pragma unroll
    for (int tau = 0; tau < 8; ++tau) cst[tau] = 0.0f;

    __builtin_amdgcn_s_barrier();  // #1: gx[0],gx[1] ready

    for (int e = 0; e < T_STEPS / 2; ++e) {
#pragma unroll
      for (int s = 0; s < 2; ++s) {
        const int slot = (2 * e + s) & 3;
        float4v gxv[8];
#pragma unroll
        for (int tau = 0; tau < 8; ++tau)
          gxv[tau] =
              *(const float4v*)(gxb + ((slot * 8 + tau) * 64 + lane) * 4);
        __builtin_amdgcn_s_setprio(1);
        float hv[8];
#pragma unroll
        for (int tau = 0; tau < 8; ++tau) {
          const float4v acc = mfma32(wfh[tau], hB, gxv[tau]);
          const float iv = sigm_(acc[0]);
          const float fv = sigm_(acc[1]);
          const float gv = tanh_(acc[2]);
          const float ov = sigm_(acc[3]);
          const float cv = fv * cst[tau] + iv * gv;
          cst[tau] = cv;
          hv[tau] = ov * tanh_(cv);
        }
        union { short8v s8; unsigned u[4]; } hu;
        hu.u[0] = cvt_pk_bf16(hv[0], hv[1]);
        hu.u[1] = cvt_pk_bf16(hv[2], hv[3]);
        hu.u[2] = cvt_pk_bf16(hv[4], hv[5]);
        hu.u[3] = cvt_pk_bf16(hv[6], hv[7]);
        hB = hu.s8;
        __builtin_amdgcn_s_setprio(0);
      }
      __builtin_amdgcn_s_barrier();  // epoch handoff
    }

    // epilogue: out = relu(h @ Wo^T + bo); B-operand = lane's own hB
#pragma unroll
    for (int ot = 0; ot < 2; ++ot) {
      const float* wor = Wo + (ot * 16 + c) * 32;
      short8v w8;
#pragma unroll
      for (int e2 = 0; e2 < 8; ++e2) w8[e2] = bf16r(wor[q * 8 + e2]);
      float4v o4 = {0.0f, 0.0f, 0.0f, 0.0f};
      o4 = mfma32(w8, hB, o4);
      float4v res;
#pragma unroll
      for (int r = 0; r < 4; ++r)
        res[r] = fmaxf(o4[r] + bo[ot * 16 + q * 4 + r], 0.0f);
      *(float4v*)(outf + (size_t)(n0 + c) * 32 + ot * 16 + q * 4) = res;
    }
  } else {
    // ------------------------- PRODUCER p --------------------------------
    const int p = wid - 1;  // 0 or 1
    stageslot(p);
    stageslot(2 + p);
    stageslot(4 + p);

    // stationary weights: all 8 tiles. A-row c -> Wih row G.
    short8v wfx[8][NK32];
    float4v binit[8];
#pragma unroll
    for (int tau = 0; tau < 8; ++tau) {
      const float* wr = Wih + ((c & 3) * 32 + (c >> 2) * 8 + tau) * D;
#pragma unroll
      for (int kt = 0; kt < NK32; ++kt) {
        short8v s8;
#pragma unroll
        for (int e = 0; e < 8; ++e) {
          const int d = kt * 32 + q * 8 + e;
          s8[e] = (d < D) ? bf16r(wr[d]) : (short)0;
        }
        wfx[tau][kt] = s8;
      }
#pragma unroll
      for (int r = 0; r < 4; ++r) {
        const int Gr = r * 32 + q * 8 + tau;  // C reg r -> gate r, unit q*8+tau
        binit[tau][r] = bih[Gr] + bhh[Gr];
      }
    }

    auto produce = [&](int k) {
      const float* xs = xbuf + (k & 7) * FPS + c * D;
      short8v xN[NK32];
#pragma unroll
      for (int kt = 0; kt < NK32; ++kt) {
        const float* pp = xs + kt * 32 + q * 8;
        const float2v r0 = *(const float2v*)(pp);
        const float2v r1 = *(const float2v*)(pp + 2);
        const float2v r2 = *(const float2v*)(pp + 4);
        const float2v r3 = *(const float2v*)(pp + 6);
        union { short8v s; unsigned u[4]; } fr;
        fr.u[0] = cvt_pk_bf16(r0[0], r0[1]);
        fr.u[1] = cvt_pk_bf16(r1[0], r1[1]);
        fr.u[2] = cvt_pk_bf16(r2[0], r2[1]);
        fr.u[3] = cvt_pk_bf16(r3[0], r3[1]);
        xN[kt] = fr.s;
      }
      const int slot = k & 3;
#pragma unroll
      for (int tau = 0; tau < 8; ++tau) {
        float4v g4 = binit[tau];
#pragma unroll
        for (int kt = 0; kt < NK32; ++kt) g4 = mfma32(wfx[tau][kt], xN[kt], g4);
        *(float4v*)(gxb + ((slot * 8 + tau) * 64 + lane) * 4) = g4;
      }
    };

    // prologue: x[p] landed (oldest of 3 staged slots)
    if constexpr (LPS == 5)
      asm volatile("s_waitcnt vmcnt(10)" ::: "memory");
    else
      asm volatile("s_waitcnt vmcnt(6)" ::: "memory");
    produce(p);  // gx[0] by p=0, gx[1] by p=1
    LGKM0;
    __builtin_amdgcn_s_barrier();  // #1

    for (int e = 0; e < T_STEPS / 2; ++e) {
      const int k = 2 * e + 2 + p;
      if (k < T_STEPS) {
        // x[k] staged 2 epochs ago: all but the newest LPS loads landed
        if constexpr (LPS == 5)
          asm volatile("s_waitcnt vmcnt(5)" ::: "memory");
        else
          asm volatile("s_waitcnt vmcnt(3)" ::: "memory");
        produce(k);
        if (k + 4 < T_STEPS) stageslot(k + 4);
        LGKM0;  // gx writes drained
      }
      __builtin_amdgcn_s_barrier();  // epoch handoff
    }
  }
}

__global__ __launch_bounds__(192, 1) void lstm_both(
    const float* __restrict__ a, const float* __restrict__ v,
    const float* __restrict__ aWih, const float* __restrict__ aWhh,
    const float* __restrict__ abih, const float* __restrict__ abhh,
    const float* __restrict__ aWo, const float* __restrict__ abo,
    const float* __restrict__ vWih, const float* __restrict__ vWhh,
    const float* __restrict__ vbih, const float* __restrict__ vbhh,
    const float* __restrict__ vWo, const float* __restrict__ vbo,
    float* __restrict__ afw, float* __restrict__ vfw) {
  __shared__ __align__(16) char smem[SMEM_BYTES];
  const int b = blockIdx.x;
  if (b < 256)
    lstm_ll<74, 3, 5>(a, aWih, aWhh, abih, abhh, aWo, abo, afw, b * 16, smem);
  else
    lstm_ll<47, 2, 3>(v, vWih, vWhh, vbih, vbhh, vWo, vbo, vfw,
                      (b - 256) * 16, smem);
}

// ---------------------------------------------------------------------------
// lf = relu(relu(l @ lW1^T + lb1) @ lW2^T + lb2)   [4096,768]->[4096,32]
// ---------------------------------------------------------------------------
__global__ __launch_bounds__(256) void lf_kernel(
    const float* __restrict__ l, const float* __restrict__ lW1,
    const float* __restrict__ lb1, const float* __restrict__ lW2,
    const float* __restrict__ lb2, float* __restrict__ lf) {
  __shared__ __align__(16) float lsh[16 * 768];
  __shared__ __align__(16) float h1sh[16 * 128];
  const int tid = threadIdx.x;
  const int n0 = blockIdx.x * 16;

  {
    const float4v* src = (const float4v*)(l + (size_t)n0 * 768);
    float4v* dst = (float4v*)lsh;
#pragma unroll
    for (int i = 0; i < 12; ++i) dst[tid + i * 256] = src[tid + i * 256];
  }
  __syncthreads();

  {
    const int u = tid & 127;
    const int sg = tid >> 7;
    float acc[8];
#pragma unroll
    for (int i = 0; i < 8; ++i) acc[i] = 0.0f;
    const float4v* wrow = (const float4v*)(lW1 + u * 768);
    for (int k4 = 0; k4 < 192; ++k4) {
      const float4v w = wrow[k4];
#pragma unroll
      for (int i = 0; i < 8; ++i) {
        const float4v xv = ((const float4v*)(lsh + (sg * 8 + i) * 768))[k4];
        acc[i] += w[0] * xv[0] + w[1] * xv[1] + w[2] * xv[2] + w[3] * xv[3];
      }
    }
    const float b = lb1[u];
#pragma unroll
    for (int i = 0; i < 8; ++i)
      h1sh[(sg * 8 + i) * 128 + u] = fmaxf(acc[i] + b, 0.0f);
  }
  __syncthreads();

  {
    const int u2 = tid & 31;
    const int sg2 = tid >> 5;
    float acc0 = 0.0f, acc1 = 0.0f;
    const float4v* w2 = (const float4v*)(lW2 + u2 * 128);
#pragma unroll
    for (int k4 = 0; k4 < 32; ++k4) {
      const float4v w = w2[k4];
      const float4v xa = ((const float4v*)(h1sh + sg2 * 128))[k4];
      const float4v xb = ((const float4v*)(h1sh + (sg2 + 8) * 128))[k4];
      acc0 += w[0] * xa[0] + w[1] * xa[1] + w[2] * xa[2] + w[3] * xa[3];
      acc1 += w[0] * xb[0] + w[1] * xb[1] + w[2] * xb[2] + w[3] * xb[3];
    }
    const float b2 = lb2[u2];
    lf[(size_t)(n0 + sg2) * 32 + u2] = fmaxf(acc0 + b2, 0.0f);
    lf[(size_t)(n0 + sg2 + 8) * 32 + u2] = fmaxf(acc1 + b2, 0.0f);
  }
}

// ---------------------------------------------------------------------------
// Transformer block + post-fusion head. 32 lanes/sample, 8 samples/block.
// ---------------------------------------------------------------------------
__global__ __launch_bounds__(256) void head_kernel(
    const float* __restrict__ lf, const float* __restrict__ af,
    const float* __restrict__ vf, const float* __restrict__ Wq,
    const float* __restrict__ bq, const float* __restrict__ Wk,
    const float* __restrict__ bk, const float* __restrict__ Wv,
    const float* __restrict__ bv, const float* __restrict__ Wz,
    const float* __restrict__ bz, const float* __restrict__ Wff,
    const float* __restrict__ bff, const float* __restrict__ g1,
    const float* __restrict__ be1, const float* __restrict__ g2,
    const float* __restrict__ be2, const float* __restrict__ Wp1,
    const float* __restrict__ bp1, const float* __restrict__ Wp2,
    const float* __restrict__ bp2, float* __restrict__ out) {
  __shared__ float shA[8][3][33];
  __shared__ float shB[8][3][33];
  const int tid = threadIdx.x;
  const int j = tid & 31;
  const int slot = tid >> 5;
  const int n = blockIdx.x * 8 + slot;
  const size_t off = (size_t)n * 32 + j;

  const float x0 = lf[off], x1 = af[off], x2 = vf[off];

  auto ln3 = [&](float a0, float a1, float a2, const float* g,
                 const float* be, float* o) {
    float s = a0 + a1 + a2;
    s += __shfl_xor(s, 1); s += __shfl_xor(s, 2); s += __shfl_xor(s, 4);
    s += __shfl_xor(s, 8); s += __shfl_xor(s, 16);
    const float mu = s * (1.0f / 96.0f);
    const float d0 = a0 - mu, d1 = a1 - mu, d2 = a2 - mu;
    float ss = d0 * d0 + d1 * d1 + d2 * d2;
    ss += __shfl_xor(ss, 1); ss += __shfl_xor(ss, 2); ss += __shfl_xor(ss, 4);
    ss += __shfl_xor(ss, 8); ss += __shfl_xor(ss, 16);
    const float rs = rsqrtf(ss * (1.0f / 96.0f) + 1e-5f);
    o[0] = d0 * rs * g[j] + be[j];
    o[1] = d1 * rs * g[32 + j] + be[32 + j];
    o[2] = d2 * rs * g[64 + j] + be[64 + j];
  };

  float z[3];
  ln3(x0, x1, x2, g1, be1, z);
  shA[slot][0][j] = z[0]; shA[slot][1][j] = z[1]; shA[slot][2][j] = z[2];
  __syncthreads();

  float qv[3], kv[3], vv[3];
  {
    const float bqj = bq[j], bkj = bk[j], bvj = bv[j];
    qv[0] = bqj; qv[1] = bqj; qv[2] = bqj;
    kv[0] = bkj; kv[1] = bkj; kv[2] = bkj;
    vv[0] = bvj; vv[1] = bvj; vv[2] = bvj;
    const float* wqr = Wq + j * 32;
    const float* wkr = Wk + j * 32;
    const float* wvr = Wv + j * 32;
#pragma unroll 8
    for (int k = 0; k < 32; ++k) {
      const float zz0 = shA[slot][0][k], zz1 = shA[slot][1][k],
                  zz2 = shA[slot][2][k];
      const float wq = wqr[k], wk_ = wkr[k], wv_ = wvr[k];
      qv[0] += wq * zz0;  qv[1] += wq * zz1;  qv[2] += wq * zz2;
      kv[0] += wk_ * zz0; kv[1] += wk_ * zz1; kv[2] += wk_ * zz2;
      vv[0] += wv_ * zz0; vv[1] += wv_ * zz1; vv[2] += wv_ * zz2;
    }
  }

  float at[3][3];
#pragma unroll
  for (int s = 0; s < 3; ++s)
#pragma unroll
    for (int t2 = 0; t2 < 3; ++t2) {
      float p = qv[s] * kv[t2];
      p += __shfl_xor(p, 1); p += __shfl_xor(p, 2); p += __shfl_xor(p, 4);
      at[s][t2] = p;
    }
#pragma unroll
  for (int s = 0; s < 3; ++s) {
    const float m = fmaxf(fmaxf(at[s][0], at[s][1]), at[s][2]);
    const float e0 = __expf(at[s][0] - m), e1 = __expf(at[s][1] - m),
                e2 = __expf(at[s][2] - m);
    const float sc = 0.35355339059327373f * __fdividef(1.0f, e0 + e1 + e2);
    at[s][0] = e0 * sc; at[s][1] = e1 * sc; at[s][2] = e2 * sc;
  }
  float zc[3];
#pragma unroll
  for (int s = 0; s < 3; ++s)
    zc[s] = at[s][0] * vv[0] + at[s][1] * vv[1] + at[s][2] * vv[2];
  shB[slot][0][j] = zc[0]; shB[slot][1][j] = zc[1]; shB[slot][2][j] = zc[2];
  __syncthreads();

  const float bzj = bz[j];
  float z2a[3] = {bzj + x0, bzj + x1, bzj + x2};
  {
    const float* wzr = Wz + j * 32;
#pragma unroll 8
    for (int k = 0; k < 32; ++k) {
      const float w = wzr[k];
      z2a[0] += w * shB[slot][0][k];
      z2a[1] += w * shB[slot][1][k];
      z2a[2] += w * shB[slot][2][k];
    }
  }

  float zn[3];
  ln3(z2a[0], z2a[1], z2a[2], g2, be2, zn);
  shA[slot][0][j] = zn[0]; shA[slot][1][j] = zn[1]; shA[slot][2][j] = zn[2];
  __syncthreads();

  const float bffj = bff[j];
  float Za[3] = {bffj + z2a[0], bffj + z2a[1], bffj + z2a[2]};
  {
    const float* wfr = Wff + j * 32;
#pragma unroll 8
    for (int k = 0; k < 32; ++k) {
      const float w = wfr[k];
      Za[0] += w * shA[slot][0][k];
      Za[1] += w * shA[slot][1][k];
      Za[2] += w * shA[slot][2][k];
    }
  }
  shB[slot][0][j] = Za[0]; shB[slot][1][j] = Za[1]; shB[slot][2][j] = Za[2];
  __syncthreads();

  float p = bp1[j];
  {
    const float* wpr = Wp1 + j * 96;
#pragma unroll
    for (int s = 0; s < 3; ++s)
#pragma unroll 8
      for (int k = 0; k < 32; ++k) p += wpr[s * 32 + k] * shB[slot][s][k];
  }
  p = fmaxf(p, 0.0f);
  float l0 = Wp2[j] * p, l1 = Wp2[32 + j] * p;
  l0 += __shfl_xor(l0, 1); l0 += __shfl_xor(l0, 2); l0 += __shfl_xor(l0, 4);
  l0 += __shfl_xor(l0, 8); l0 += __shfl_xor(l0, 16);
  l1 += __shfl_xor(l1, 1); l1 += __shfl_xor(l1, 2); l1 += __shfl_xor(l1, 4);
  l1 += __shfl_xor(l1, 8); l1 += __shfl_xor(l1, 16);
  l0 += bp2[0]; l1 += bp2[1];
  const float mx = fmaxf(l0, l1);
  const float e0 = __expf(l0 - mx), e1 = __expf(l1 - mx);
  const float inv = __fdividef(1.0f, e0 + e1);
  if (j == 0) {
    out[(size_t)n * 2 + 0] = e0 * inv;
    out[(size_t)n * 2 + 1] = e1 * inv;
  }
}

// ---------------------------------------------------------------------------
extern "C" void kernel_launch(void* const* d_in, const int* in_sizes, int n_in,
                              void* d_out, int out_size, void* d_ws,
                              size_t ws_size, hipStream_t stream) {
  const float* l    = (const float*)d_in[0];
  const float* a    = (const float*)d_in[1];
  const float* v    = (const float*)d_in[2];
  const float* lW1  = (const float*)d_in[3];
  const float* lb1  = (const float*)d_in[4];
  const float* lW2  = (const float*)d_in[5];
  const float* lb2  = (const float*)d_in[6];
  const float* aWih = (const float*)d_in[7];
  const float* aWhh = (const float*)d_in[8];
  const float* abih = (const float*)d_in[9];
  const float* abhh = (const float*)d_in[10];
  const float* aWo  = (const float*)d_in[11];
  const float* abo  = (const float*)d_in[12];
  const float* vWih = (const float*)d_in[13];
  const float* vWhh = (const float*)d_in[14];
  const float* vbih = (const float*)d_in[15];
  const float* vbhh = (const float*)d_in[16];
  const float* vWo  = (const float*)d_in[17];
  const float* vbo  = (const float*)d_in[18];
  const float* Wq   = (const float*)d_in[19];
  const float* bq   = (const float*)d_in[20];
  const float* Wk   = (const float*)d_in[21];
  const float* bk   = (const float*)d_in[22];
  const float* Wv   = (const float*)d_in[23];
  const float* bv   = (const float*)d_in[24];
  const float* Wz   = (const float*)d_in[25];
  const float* bz   = (const float*)d_in[26];
  const float* Wff  = (const float*)d_in[27];
  const float* bff  = (const float*)d_in[28];
  const float* g1   = (const float*)d_in[29];
  const float* be1  = (const float*)d_in[30];
  const float* g2   = (const float*)d_in[31];
  const float* be2  = (const float*)d_in[32];
  const float* Wp1  = (const float*)d_in[33];
  const float* bp1  = (const float*)d_in[34];
  const float* Wp2  = (const float*)d_in[35];
  const float* bp2  = (const float*)d_in[36];

  float* out = (float*)d_out;
  float* ws = (float*)d_ws;
  float* lfw = ws;
  float* afw = ws + 4096 * 32;
  float* vfw = ws + 2 * 4096 * 32;

  hipLaunchKernelGGL(lstm_both, dim3(512), dim3(192), 0, stream, a, v, aWih,
                     aWhh, abih, abhh, aWo, abo, vWih, vWhh, vbih, vbhh, vWo,
                     vbo, afw, vfw);
  hipLaunchKernelGGL(lf_kernel, dim3(256), dim3(256), 0, stream, l, lW1, lb1,
                     lW2, lb2, lfw);
  hipLaunchKernelGGL(head_kernel, dim3(512), dim3(256), 0, stream, lfw, afw,
                     vfw, Wq, bq, Wk, bk, Wv, bv, Wz, bz, Wff, bff, g1, be1,
                     g2, be2, Wp1, bp1, Wp2, bp2, out);
}

// Round 11
// 304.605 us; speedup vs baseline: 1.5013x; 1.5013x over previous
//
#include <hip/hip_runtime.h>

// ---------------------------------------------------------------------------
// Fused multimodal net: l-MLP + 2 LSTMs (MFMA bf16, LDS-staged) + tiny
// transformer head. N=4096, T=256, DA=74, DV=47, hidden=32.
//
// LSTM (r8 champion structure + small-LDS ring for occupancy):
// block = 128 threads = 2 waves per 16-sample group, 512 groups.
// Row map: gate row G = r*32 + wid*16 + q*4 + tau -> lane (q,c) tile tau
// C-regs 0..3 = i,f,g,o of unit wid*16+q*4+tau; lane's 4 h values contiguous
// => 2 cvt_pk + 1 ds_write_b64; h via ping-pong LDS, 1 barrier/step.
// Producer ring: step t produces gx[t+1] = bias + Wih@x[t+1] (off-chain
// MFMAs); on-chain: 1 ds_read_b128 (h) + 4 h-MFMAs + lean trans + b64 write.
// x staged via global_load_lds into a 4-SLOT ring (prefetch distance 3):
// even slots staged by wave0, odd by wave1; the stager waits vmcnt(0) one
// step after issue (its only outstanding slot), barrier publishes. LDS
// 21.5KB (a) / 14.7KB (v) => ~7 blocks/CU, 3.5 waves/SIMD for stall overlap
// (vs 40.5KB/11% occupancy in r8).
// ---------------------------------------------------------------------------

typedef float float4v __attribute__((ext_vector_type(4)));
typedef float float2v __attribute__((ext_vector_type(2)));
typedef short short8v __attribute__((ext_vector_type(8)));
typedef unsigned uint2v __attribute__((ext_vector_type(2)));

#define N_SAMPLES 4096
#define T_STEPS 256
#define HSTR 40           // shorts per sample row in H (32 units + pad)
#define HBUF (16 * HSTR)  // shorts per H buffer

#define LGKM0 asm volatile("s_waitcnt lgkmcnt(0)" ::: "memory")
#define VM0 asm volatile("s_waitcnt vmcnt(0)" ::: "memory")

__device__ __forceinline__ short bf16r(float f) {
  unsigned u = __float_as_uint(f);
  u += 0x7FFFu + ((u >> 16) & 1u);
  return (short)(u >> 16);
}
__device__ __forceinline__ unsigned cvt_pk_bf16(float lo, float hi) {
  unsigned r;
  asm("v_cvt_pk_bf16_f32 %0, %1, %2" : "=v"(r) : "v"(lo), "v"(hi));
  return r;
}
__device__ __forceinline__ float sigm_(float x) {
  return __builtin_amdgcn_rcpf(1.0f +
                               __builtin_amdgcn_exp2f(x * -1.44269504f));
}
__device__ __forceinline__ float tanh_(float x) {
  return 1.0f - 2.0f * __builtin_amdgcn_rcpf(
                           1.0f + __builtin_amdgcn_exp2f(x * 2.88539009f));
}
__device__ __forceinline__ float4v mfma32(short8v a, short8v b, float4v c) {
  return __builtin_amdgcn_mfma_f32_16x16x32_bf16(a, b, c, 0, 0, 0);
}
__device__ __forceinline__ void gld16(const float* g, float* l) {
  __builtin_amdgcn_global_load_lds(
      (const __attribute__((address_space(1))) unsigned int*)g,
      (__attribute__((address_space(3))) unsigned int*)l, 16, 0, 0);
}

// LDS: x ring 4*16*74*4 = 18944 + pad 64 + H 2*640*2 = 2560 => 21568
#define SMEM_BYTES (4 * 16 * 74 * 4 + 64 + 2 * HBUF * 2)

template <int D, int NK32>
__device__ void lstm2w(const float* __restrict__ x,
                       const float* __restrict__ Wih,
                       const float* __restrict__ Whh,
                       const float* __restrict__ bih,
                       const float* __restrict__ bhh,
                       const float* __restrict__ Wo,
                       const float* __restrict__ bo,
                       float* __restrict__ outf, int n0, char* smem) {
  constexpr int FPS = 16 * D;    // floats per ring slot
  constexpr int UPS = FPS / 4;   // 16B units per slot
  constexpr int FULL = UPS / 64;
  constexpr int REM = UPS % 64;

  float* xbuf = (float*)smem;                                   // [4][FPS]
  unsigned short* Hu = (unsigned short*)(smem + 4 * FPS * 4 + 64);

  const int tid = threadIdx.x;
  const int wid = tid >> 6;   // 0..1
  const int lane = tid & 63;
  const int c = lane & 15;
  const int q = lane >> 4;

  auto stageslot = [&](int t) {
    const float* gs = x + (size_t)t * (N_SAMPLES * D) + (size_t)n0 * D;
    float* ls = xbuf + (t & 3) * FPS;
#pragma unroll
    for (int r = 0; r < FULL; ++r)
      gld16(gs + (r * 64 + lane) * 4, ls + r * 256);
    if (REM) {
      if (lane < REM) gld16(gs + (FULL * 64 + lane) * 4, ls + FULL * 256);
    }
  };

  // prologue staging: even slots by wave0, odd by wave1
  if (wid == 0) { stageslot(0); stageslot(2); }
  else          { stageslot(1); }

  // stationary weights: 4 tiles (16 units) per wave; weight zeros beyond D
  // carry the x tail masking implicitly.
  short8v wfx[4][NK32], wfh[4];
  float4v binit[4];
#pragma unroll
  for (int T = 0; T < 4; ++T) {
    const int G = (c & 3) * 32 + wid * 16 + (c >> 2) * 4 + T;  // A-row c
    const float* wr = Wih + G * D;
#pragma unroll
    for (int kt = 0; kt < NK32; ++kt) {
      short8v s;
#pragma unroll
      for (int e = 0; e < 8; ++e) {
        const int d = kt * 32 + q * 8 + e;
        s[e] = (d < D) ? bf16r(wr[d]) : (short)0;
      }
      wfx[T][kt] = s;
    }
    const float* hr = Whh + G * 32;
#pragma unroll
    for (int e = 0; e < 8; ++e) wfh[T][e] = bf16r(hr[q * 8 + e]);
#pragma unroll
    for (int r = 0; r < 4; ++r) {
      const int Gr = r * 32 + wid * 16 + q * 4 + T;  // C reg r mapping
      binit[T][r] = bih[Gr] + bhh[Gr];
    }
  }

  // zero both H buffers
  {
    unsigned* Hz = (unsigned*)Hu;
    for (int i = tid; i < 640; i += 128) Hz[i] = 0;
  }

  VM0;    // own prologue slots landed
  LGKM0;  // H zeros visible
  __builtin_amdgcn_s_barrier();

  auto ldcvt = [&](const float* xs0, short8v* xo) {
    const float* xs = xs0 + c * D;
#pragma unroll
    for (int kt = 0; kt < NK32; ++kt) {
      const float* p = xs + kt * 32 + q * 8;
      const float2v r0 = *(const float2v*)(p);
      const float2v r1 = *(const float2v*)(p + 2);
      const float2v r2 = *(const float2v*)(p + 4);
      const float2v r3 = *(const float2v*)(p + 6);
      union { short8v s; unsigned u[4]; } fr;
      fr.u[0] = cvt_pk_bf16(r0[0], r0[1]);
      fr.u[1] = cvt_pk_bf16(r1[0], r1[1]);
      fr.u[2] = cvt_pk_bf16(r2[0], r2[1]);
      fr.u[3] = cvt_pk_bf16(r3[0], r3[1]);
      xo[kt] = fr.s;
    }
  };

  float cst[4] = {0.0f, 0.0f, 0.0f, 0.0f};
  float4v gxA[4], gxB[4];
  {
    short8v xF[NK32];
    ldcvt(xbuf, xF);  // slot 0 = x[0]
#pragma unroll
    for (int T = 0; T < 4; ++T) {
      float4v g4 = binit[T];
#pragma unroll
      for (int kt = 0; kt < NK32; ++kt) g4 = mfma32(wfx[T][kt], xF[kt], g4);
      gxA[T] = g4;
    }
  }

  // one step; i = t&7 compile-time, gc = gates for t, gn -> gates for t+1.
  // Ring schedule: read slot (t+1)&3; stage slot (t+3)&3 by wave (t+3)&1;
  // end-of-step: stager of slot t+2 (= wave t&1) drains vmcnt(0).
  auto STEP = [&](int t, int i, float4v (&gc)[4], float4v (&gn)[4]) {
    const int pb = i & 1;
    // on-chain: h of step t-1 (all 32 units)
    const short8v hB = *(const short8v*)(Hu + pb * HBUF + c * HSTR + q * 8);
    // staging: slot (t+3)&3 by wave (i+3)&1
    if (((i + 3) & 1) == wid && t + 3 < T_STEPS) stageslot(t + 3);
    // off-chain: x[t+1] frags + production
    short8v xN[NK32];
    ldcvt(xbuf + ((i + 1) & 3) * FPS, xN);
#pragma unroll
    for (int T = 0; T < 4; ++T) {
      float4v g4 = binit[T];
#pragma unroll
      for (int kt = 0; kt < NK32; ++kt) g4 = mfma32(wfx[T][kt], xN[kt], g4);
      gn[T] = g4;
    }
    // on-chain: 4 h-MFMAs + lean trans (prioritized)
    __builtin_amdgcn_s_setprio(1);
    float hv[4];
#pragma unroll
    for (int T = 0; T < 4; ++T) {
      const float4v acc = mfma32(wfh[T], hB, gc[T]);
      const float iv = sigm_(acc[0]);
      const float fv = sigm_(acc[1]);
      const float gv = tanh_(acc[2]);
      const float ov = sigm_(acc[3]);
      const float cv = fv * cst[T] + iv * gv;
      cst[T] = cv;
      hv[T] = ov * tanh_(cv);
    }
    uint2v hp;
    hp[0] = cvt_pk_bf16(hv[0], hv[1]);
    hp[1] = cvt_pk_bf16(hv[2], hv[3]);
    *(uint2v*)(Hu + (1 - pb) * HBUF + c * HSTR + wid * 16 + q * 4) = hp;
    __builtin_amdgcn_s_setprio(0);
    LGKM0;  // h write (and ds reads) drained
    if ((i & 1) == wid) { VM0; }  // drain own slot t+2 stage (issued t-1)
    __builtin_amdgcn_s_barrier();
  };

  for (int tb = 0; tb < T_STEPS; tb += 8) {
    STEP(tb + 0, 0, gxA, gxB);
    STEP(tb + 1, 1, gxB, gxA);
    STEP(tb + 2, 2, gxA, gxB);
    STEP(tb + 3, 3, gxB, gxA);
    STEP(tb + 4, 4, gxA, gxB);
    STEP(tb + 5, 5, gxB, gxA);
    STEP(tb + 6, 6, gxA, gxB);
    STEP(tb + 7, 7, gxB, gxA);
  }

  // epilogue: h[255] in H buffer 0 (t=255 odd writes pb^1=0)
  {
    const short8v hB = *(const short8v*)(Hu + c * HSTR + q * 8);
    const float* wor = Wo + (16 * wid + c) * 32;
    short8v w8;
#pragma unroll
    for (int e = 0; e < 8; ++e) w8[e] = bf16r(wor[q * 8 + e]);
    float4v o4 = {0.0f, 0.0f, 0.0f, 0.0f};
    o4 = mfma32(w8, hB, o4);
    float4v res;
#pragma unroll
    for (int r = 0; r < 4; ++r)
      res[r] = fmaxf(o4[r] + bo[16 * wid + q * 4 + r], 0.0f);
    *(float4v*)(outf + (size_t)(n0 + c) * 32 + 16 * wid + q * 4) = res;
  }
}

__global__ __launch_bounds__(128, 3) void lstm_both(
    const float* __restrict__ a, const float* __restrict__ v,
    const float* __restrict__ aWih, const float* __restrict__ aWhh,
    const float* __restrict__ abih, const float* __restrict__ abhh,
    const float* __restrict__ aWo, const float* __restrict__ abo,
    const float* __restrict__ vWih, const float* __restrict__ vWhh,
    const float* __restrict__ vbih, const float* __restrict__ vbhh,
    const float* __restrict__ vWo, const float* __restrict__ vbo,
    float* __restrict__ afw, float* __restrict__ vfw) {
  __shared__ __align__(16) char smem[SMEM_BYTES];
  const int b = blockIdx.x;
  if (b < 256)
    lstm2w<74, 3>(a, aWih, aWhh, abih, abhh, aWo, abo, afw, b * 16, smem);
  else
    lstm2w<47, 2>(v, vWih, vWhh, vbih, vbhh, vWo, vbo, vfw,
                  (b - 256) * 16, smem);
}

// ---------------------------------------------------------------------------
// lf = relu(relu(l @ lW1^T + lb1) @ lW2^T + lb2)   [4096,768]->[4096,32]
// ---------------------------------------------------------------------------
__global__ __launch_bounds__(256) void lf_kernel(
    const float* __restrict__ l, const float* __restrict__ lW1,
    const float* __restrict__ lb1, const float* __restrict__ lW2,
    const float* __restrict__ lb2, float* __restrict__ lf) {
  __shared__ __align__(16) float lsh[16 * 768];
  __shared__ __align__(16) float h1sh[16 * 128];
  const int tid = threadIdx.x;
  const int n0 = blockIdx.x * 16;

  {
    const float4v* src = (const float4v*)(l + (size_t)n0 * 768);
    float4v* dst = (float4v*)lsh;
#pragma unroll
    for (int i = 0; i < 12; ++i) dst[tid + i * 256] = src[tid + i * 256];
  }
  __syncthreads();

  {
    const int u = tid & 127;
    const int sg = tid >> 7;
    float acc[8];
#pragma unroll
    for (int i = 0; i < 8; ++i) acc[i] = 0.0f;
    const float4v* wrow = (const float4v*)(lW1 + u * 768);
    for (int k4 = 0; k4 < 192; ++k4) {
      const float4v w = wrow[k4];
#pragma unroll
      for (int i = 0; i < 8; ++i) {
        const float4v xv = ((const float4v*)(lsh + (sg * 8 + i) * 768))[k4];
        acc[i] += w[0] * xv[0] + w[1] * xv[1] + w[2] * xv[2] + w[3] * xv[3];
      }
    }
    const float b = lb1[u];
#pragma unroll
    for (int i = 0; i < 8; ++i)
      h1sh[(sg * 8 + i) * 128 + u] = fmaxf(acc[i] + b, 0.0f);
  }
  __syncthreads();

  {
    const int u2 = tid & 31;
    const int sg2 = tid >> 5;
    float acc0 = 0.0f, acc1 = 0.0f;
    const float4v* w2 = (const float4v*)(lW2 + u2 * 128);
#pragma unroll
    for (int k4 = 0; k4 < 32; ++k4) {
      const float4v w = w2[k4];
      const float4v xa = ((const float4v*)(h1sh + sg2 * 128))[k4];
      const float4v xb = ((const float4v*)(h1sh + (sg2 + 8) * 128))[k4];
      acc0 += w[0] * xa[0] + w[1] * xa[1] + w[2] * xa[2] + w[3] * xa[3];
      acc1 += w[0] * xb[0] + w[1] * xb[1] + w[2] * xb[2] + w[3] * xb[3];
    }
    const float b2 = lb2[u2];
    lf[(size_t)(n0 + sg2) * 32 + u2] = fmaxf(acc0 + b2, 0.0f);
    lf[(size_t)(n0 + sg2 + 8) * 32 + u2] = fmaxf(acc1 + b2, 0.0f);
  }
}

// ---------------------------------------------------------------------------
// Transformer block + post-fusion head. 32 lanes/sample, 8 samples/block.
// ---------------------------------------------------------------------------
__global__ __launch_bounds__(256) void head_kernel(
    const float* __restrict__ lf, const float* __restrict__ af,
    const float* __restrict__ vf, const float* __restrict__ Wq,
    const float* __restrict__ bq, const float* __restrict__ Wk,
    const float* __restrict__ bk, const float* __restrict__ Wv,
    const float* __restrict__ bv, const float* __restrict__ Wz,
    const float* __restrict__ bz, const float* __restrict__ Wff,
    const float* __restrict__ bff, const float* __restrict__ g1,
    const float* __restrict__ be1, const float* __restrict__ g2,
    const float* __restrict__ be2, const float* __restrict__ Wp1,
    const float* __restrict__ bp1, const float* __restrict__ Wp2,
    const float* __restrict__ bp2, float* __restrict__ out) {
  __shared__ float shA[8][3][33];
  __shared__ float shB[8][3][33];
  const int tid = threadIdx.x;
  const int j = tid & 31;
  const int slot = tid >> 5;
  const int n = blockIdx.x * 8 + slot;
  const size_t off = (size_t)n * 32 + j;

  const float x0 = lf[off], x1 = af[off], x2 = vf[off];

  auto ln3 = [&](float a0, float a1, float a2, const float* g,
                 const float* be, float* o) {
    float s = a0 + a1 + a2;
    s += __shfl_xor(s, 1); s += __shfl_xor(s, 2); s += __shfl_xor(s, 4);
    s += __shfl_xor(s, 8); s += __shfl_xor(s, 16);
    const float mu = s * (1.0f / 96.0f);
    const float d0 = a0 - mu, d1 = a1 - mu, d2 = a2 - mu;
    float ss = d0 * d0 + d1 * d1 + d2 * d2;
    ss += __shfl_xor(ss, 1); ss += __shfl_xor(ss, 2); ss += __shfl_xor(ss, 4);
    ss += __shfl_xor(ss, 8); ss += __shfl_xor(ss, 16);
    const float rs = rsqrtf(ss * (1.0f / 96.0f) + 1e-5f);
    o[0] = d0 * rs * g[j] + be[j];
    o[1] = d1 * rs * g[32 + j] + be[32 + j];
    o[2] = d2 * rs * g[64 + j] + be[64 + j];
  };

  float z[3];
  ln3(x0, x1, x2, g1, be1, z);
  shA[slot][0][j] = z[0]; shA[slot][1][j] = z[1]; shA[slot][2][j] = z[2];
  __syncthreads();

  float qv[3], kv[3], vv[3];
  {
    const float bqj = bq[j], bkj = bk[j], bvj = bv[j];
    qv[0] = bqj; qv[1] = bqj; qv[2] = bqj;
    kv[0] = bkj; kv[1] = bkj; kv[2] = bkj;
    vv[0] = bvj; vv[1] = bvj; vv[2] = bvj;
    const float* wqr = Wq + j * 32;
    const float* wkr = Wk + j * 32;
    const float* wvr = Wv + j * 32;
#pragma unroll 8
    for (int k = 0; k < 32; ++k) {
      const float zz0 = shA[slot][0][k], zz1 = shA[slot][1][k],
                  zz2 = shA[slot][2][k];
      const float wq = wqr[k], wk_ = wkr[k], wv_ = wvr[k];
      qv[0] += wq * zz0;  qv[1] += wq * zz1;  qv[2] += wq * zz2;
      kv[0] += wk_ * zz0; kv[1] += wk_ * zz1; kv[2] += wk_ * zz2;
      vv[0] += wv_ * zz0; vv[1] += wv_ * zz1; vv[2] += wv_ * zz2;
    }
  }

  float at[3][3];
#pragma unroll
  for (int s = 0; s < 3; ++s)
#pragma unroll
    for (int t2 = 0; t2 < 3; ++t2) {
      float p = qv[s] * kv[t2];
      p += __shfl_xor(p, 1); p += __shfl_xor(p, 2); p += __shfl_xor(p, 4);
      at[s][t2] = p;
    }
#pragma unroll
  for (int s = 0; s < 3; ++s) {
    const float m = fmaxf(fmaxf(at[s][0], at[s][1]), at[s][2]);
    const float e0 = __expf(at[s][0] - m), e1 = __expf(at[s][1] - m),
                e2 = __expf(at[s][2] - m);
    const float sc = 0.35355339059327373f * __fdividef(1.0f, e0 + e1 + e2);
    at[s][0] = e0 * sc; at[s][1] = e1 * sc; at[s][2] = e2 * sc;
  }
  float zc[3];
#pragma unroll
  for (int s = 0; s < 3; ++s)
    zc[s] = at[s][0] * vv[0] + at[s][1] * vv[1] + at[s][2] * vv[2];
  shB[slot][0][j] = zc[0]; shB[slot][1][j] = zc[1]; shB[slot][2][j] = zc[2];
  __syncthreads();

  const float bzj = bz[j];
  float z2a[3] = {bzj + x0, bzj + x1, bzj + x2};
  {
    const float* wzr = Wz + j * 32;
#pragma unroll 8
    for (int k = 0; k < 32; ++k) {
      const float w = wzr[k];
      z2a[0] += w * shB[slot][0][k];
      z2a[1] += w * shB[slot][1][k];
      z2a[2] += w * shB[slot][2][k];
    }
  }

  float zn[3];
  ln3(z2a[0], z2a[1], z2a[2], g2, be2, zn);
  shA[slot][0][j] = zn[0]; shA[slot][1][j] = zn[1]; shA[slot][2][j] = zn[2];
  __syncthreads();

  const float bffj = bff[j];
  float Za[3] = {bffj + z2a[0], bffj + z2a[1], bffj + z2a[2]};
  {
    const float* wfr = Wff + j * 32;
#pragma unroll 8
    for (int k = 0; k < 32; ++k) {
      const float w = wfr[k];
      Za[0] += w * shA[slot][0][k];
      Za[1] += w * shA[slot][1][k];
      Za[2] += w * shA[slot][2][k];
    }
  }
  shB[slot][0][j] = Za[0]; shB[slot][1][j] = Za[1]; shB[slot][2][j] = Za[2];
  __syncthreads();

  float p = bp1[j];
  {
    const float* wpr = Wp1 + j * 96;
#pragma unroll
    for (int s = 0; s < 3; ++s)
#pragma unroll 8
      for (int k = 0; k < 32; ++k) p += wpr[s * 32 + k] * shB[slot][s][k];
  }
  p = fmaxf(p, 0.0f);
  float l0 = Wp2[j] * p, l1 = Wp2[32 + j] * p;
  l0 += __shfl_xor(l0, 1); l0 += __shfl_xor(l0, 2); l0 += __shfl_xor(l0, 4);
  l0 += __shfl_xor(l0, 8); l0 += __shfl_xor(l0, 16);
  l1 += __shfl_xor(l1, 1); l1 += __shfl_xor(l1, 2); l1 += __shfl_xor(l1, 4);
  l1 += __shfl_xor(l1, 8); l1 += __shfl_xor(l1, 16);
  l0 += bp2[0]; l1 += bp2[1];
  const float mx = fmaxf(l0, l1);
  const float e0 = __expf(l0 - mx), e1 = __expf(l1 - mx);
  const float inv = __fdividef(1.0f, e0 + e1);
  if (j == 0) {
    out[(size_t)n * 2 + 0] = e0 * inv;
    out[(size_t)n * 2 + 1] = e1 * inv;
  }
}

// ---------------------------------------------------------------------------
extern "C" void kernel_launch(void* const* d_in, const int* in_sizes, int n_in,
                              void* d_out, int out_size, void* d_ws,
                              size_t ws_size, hipStream_t stream) {
  const float* l    = (const float*)d_in[0];
  const float* a    = (const float*)d_in[1];
  const float* v    = (const float*)d_in[2];
  const float* lW1  = (const float*)d_in[3];
  const float* lb1  = (const float*)d_in[4];
  const float* lW2  = (const float*)d_in[5];
  const float* lb2  = (const float*)d_in[6];
  const float* aWih = (const float*)d_in[7];
  const float* aWhh = (const float*)d_in[8];
  const float* abih = (const float*)d_in[9];
  const float* abhh = (const float*)d_in[10];
  const float* aWo  = (const float*)d_in[11];
  const float* abo  = (const float*)d_in[12];
  const float* vWih = (const float*)d_in[13];
  const float* vWhh = (const float*)d_in[14];
  const float* vbih = (const float*)d_in[15];
  const float* vbhh = (const float*)d_in[16];
  const float* vWo  = (const float*)d_in[17];
  const float* vbo  = (const float*)d_in[18];
  const float* Wq   = (const float*)d_in[19];
  const float* bq   = (const float*)d_in[20];
  const float* Wk   = (const float*)d_in[21];
  const float* bk   = (const float*)d_in[22];
  const float* Wv   = (const float*)d_in[23];
  const float* bv   = (const float*)d_in[24];
  const float* Wz   = (const float*)d_in[25];
  const float* bz   = (const float*)d_in[26];
  const float* Wff  = (const float*)d_in[27];
  const float* bff  = (const float*)d_in[28];
  const float* g1   = (const float*)d_in[29];
  const float* be1  = (const float*)d_in[30];
  const float* g2   = (const float*)d_in[31];
  const float* be2  = (const float*)d_in[32];
  const float* Wp1  = (const float*)d_in[33];
  const float* bp1  = (const float*)d_in[34];
  const float* Wp2  = (const float*)d_in[35];
  const float* bp2  = (const float*)d_in[36];

  float* out = (float*)d_out;
  float* ws = (float*)d_ws;
  float* lfw = ws;
  float* afw = ws + 4096 * 32;
  float* vfw = ws + 2 * 4096 * 32;

  hipLaunchKernelGGL(lstm_both, dim3(512), dim3(128), 0, stream, a, v, aWih,
                     aWhh, abih, abhh, aWo, abo, vWih, vWhh, vbih, vbhh, vWo,
                     vbo, afw, vfw);
  hipLaunchKernelGGL(lf_kernel, dim3(256), dim3(256), 0, stream, l, lW1, lb1,
                     lW2, lb2, lfw);
  hipLaunchKernelGGL(head_kernel, dim3(512), dim3(256), 0, stream, lfw, afw,
                     vfw, Wq, bq, Wk, bk, Wv, bv, Wz, bz, Wff, bff, g1, be1,
                     g2, be2, Wp1, bp1, Wp2, bp2, out);
}